// Round 12
// baseline (165.770 us; speedup 1.0000x reference)
//
#include <hip/hip_runtime.h>
#include <hip/hip_bf16.h>
#include <math.h>

typedef __bf16 bf16;
typedef __bf16 bf16x8 __attribute__((ext_vector_type(8)));
typedef __bf16 bf16x2 __attribute__((ext_vector_type(2)));
typedef float f32x4 __attribute__((ext_vector_type(4)));
typedef float f32x16 __attribute__((ext_vector_type(16)));

#define D_MODEL 1024
#define SEQ 1024
#define BATCH 4
#define NHEAD 16
#define MTOT (BATCH*SEQ)   // 4096

// scores computed in exp2-space: fold 1/sqrt(64) * log2(e) into Q projection
#define QSCALE 0.18033688011112042f
#define MASKNEG -1e9f
#define EXP2(x) __builtin_amdgcn_exp2f(x)

// ---------------- fused f32 -> bf16 casts (7 tensors, one launch; BW-roofline) ----------------
__global__ void cast_all(const float* __restrict__ s0, const float* __restrict__ s1,
                         const float* __restrict__ s2, const float* __restrict__ s3,
                         const float* __restrict__ s4, const float* __restrict__ s5,
                         const float* __restrict__ s6,
                         bf16* d0, bf16* d1, bf16* d2, bf16* d3, bf16* d4, bf16* d5, bf16* d6) {
    int z = blockIdx.y;
    const float* s; bf16* d; int n;
    switch (z) {
        case 0: s = s0; d = d0; n = MTOT * D_MODEL; break;
        case 1: s = s1; d = d1; n = MTOT * D_MODEL; break;
        case 2: s = s2; d = d2; n = MTOT * D_MODEL; break;
        case 3: s = s3; d = d3; n = D_MODEL * D_MODEL; break;
        case 4: s = s4; d = d4; n = D_MODEL * D_MODEL; break;
        case 5: s = s5; d = d5; n = D_MODEL * D_MODEL; break;
        default: s = s6; d = d6; n = D_MODEL * D_MODEL; break;
    }
    int idx = (blockIdx.x * blockDim.x + threadIdx.x) * 8;
    int stride = gridDim.x * blockDim.x * 8;
    for (int i = idx; i < n; i += stride) {
        const float4* p = (const float4*)(s + i);
        float4 a = p[0], b = p[1];
        bf16x8 o;
        o[0] = (bf16)a.x; o[1] = (bf16)a.y; o[2] = (bf16)a.z; o[3] = (bf16)a.w;
        o[4] = (bf16)b.x; o[5] = (bf16)b.y; o[6] = (bf16)b.z; o[7] = (bf16)b.w;
        *(bf16x8*)(d + i) = o;
    }
}

// ---------------- GEMM: C[M,N] = A[M,K] @ W[N,K]^T + bias ----------------
// REGISTER-DIRECT version: no LDS, no barriers. Each wave loads its MFMA A/B
// fragments straight from global (lane group (l15,l4) = 16 rows x 64B contiguous
// per row = 16 fully-utilized lines per instr -> same line traffic as a coalesced
// 1KB load). A streams from HBM/L2; W (2MB) is L2-resident. Register double-buffer:
// prefetch tile kt+1 while computing kt. Waves fully desynced -> no LDS-burst
// convoy, no barrier drain; setprio(T5) has the desynced regime it needs.
// MODE 0: fused QKV (z=0 Q*QSCALE, z=1 K, z=2 V stored transposed VT[b][h][d][s]).
// MODE 1: plain f32 out (output projection).
template<typename OT, int MODE>
__global__ __launch_bounds__(256, 2)
void gemm_bt(const bf16* __restrict__ A0, const bf16* __restrict__ A1, const bf16* __restrict__ A2,
             const bf16* __restrict__ W0, const bf16* __restrict__ W1, const bf16* __restrict__ W2,
             const float* __restrict__ bias0, const float* __restrict__ bias1, const float* __restrict__ bias2,
             OT* __restrict__ O0, OT* __restrict__ O1, OT* __restrict__ O2) {
    constexpr int K = D_MODEL;
    constexpr int NT = K / 32;   // 32 K-steps of 32

    int z = (MODE == 0) ? blockIdx.z : 0;
    const bf16* A = (z == 0) ? A0 : (z == 1) ? A1 : A2;
    const bf16* W = (z == 0) ? W0 : (z == 1) ? W1 : W2;
    const float* bias = (z == 0) ? bias0 : (z == 1) ? bias1 : bias2;
    OT* Out = (z == 0) ? O0 : (z == 1) ? O1 : O2;

    int tid = threadIdx.x;
    int lane = tid & 63, w = tid >> 6;
    int l15 = lane & 15, l4 = lane >> 4;
    int m0 = blockIdx.x * 128;
    int n0 = blockIdx.y * 128;
    int wm = w >> 1, wn = w & 1;

    // fragment base pointers: row = (m0 + wm*64 + m*16 + l15), k-chunk = l4*8
    const bf16* Ab = A + (size_t)(m0 + wm * 64 + l15) * K + l4 * 8;
    const bf16* Bb = W + (size_t)(n0 + wn * 64 + l15) * K + l4 * 8;

    f32x4 acc[4][4] = {};
    bf16x8 a0[4], b0[4], a1[4], b1[4];

    auto load = [&](bf16x8* av, bf16x8* bv, int kt) {
#pragma unroll
        for (int m = 0; m < 4; ++m)
            av[m] = *(const bf16x8*)(Ab + (size_t)m * 16 * K + kt * 32);
#pragma unroll
        for (int n = 0; n < 4; ++n)
            bv[n] = *(const bf16x8*)(Bb + (size_t)n * 16 * K + kt * 32);
    };
    auto compute = [&](const bf16x8* av, const bf16x8* bv) {
        __builtin_amdgcn_s_setprio(1);
#pragma unroll
        for (int m = 0; m < 4; ++m)
#pragma unroll
            for (int n = 0; n < 4; ++n)
                acc[m][n] = __builtin_amdgcn_mfma_f32_16x16x32_bf16(av[m], bv[n], acc[m][n], 0, 0, 0);
        __builtin_amdgcn_s_setprio(0);
    };

    load(a0, b0, 0);
#pragma unroll 1
    for (int kt2 = 0; kt2 < NT / 2; ++kt2) {
        load(a1, b1, 2 * kt2 + 1);        // prefetch odd tile
        compute(a0, b0);                  // compute even tile (loads hide under MFMA)
        if (kt2 + 1 < NT / 2) load(a0, b0, 2 * kt2 + 2);   // prefetch next even
        compute(a1, b1);
    }

    float bload[4];
#pragma unroll
    for (int n = 0; n < 4; ++n) bload[n] = bias[n0 + wn * 64 + n * 16 + l15];

    if (MODE == 0 && z == 2) {
        // V stored transposed: VT[(b*1024 + h*64+d)][s]
#pragma unroll
        for (int m = 0; m < 4; ++m) {
            int row = m0 + wm * 64 + m * 16 + l4 * 4;
#pragma unroll
            for (int n = 0; n < 4; ++n) {
                int col = n0 + wn * 64 + n * 16 + l15;
                float bl = bload[n];
#pragma unroll
                for (int r = 0; r < 4; ++r) {
                    float vv = acc[m][n][r] + bl;
                    int rr = row + r;
                    int bb = rr >> 10, s = rr & 1023;
                    Out[((size_t)(bb * 1024 + col)) * 1024 + s] = (OT)vv;
                }
            }
        }
    } else {
        const float sc = (MODE == 0 && z == 0) ? QSCALE : 1.0f;
#pragma unroll
        for (int m = 0; m < 4; ++m) {
            int row = m0 + wm * 64 + m * 16 + l4 * 4;
#pragma unroll
            for (int n = 0; n < 4; ++n) {
                int col = n0 + wn * 64 + n * 16 + l15;
                float bl = bload[n];
#pragma unroll
                for (int r = 0; r < 4; ++r) {
                    float vv = (acc[m][n][r] + bl) * sc;
                    Out[(size_t)(row + r) * D_MODEL + col] = (OT)vv;
                }
            }
        }
    }
}

// ---------------- Flash attention fwd: intra-block split-KV, 8 waves, LOW-VGPR (R9, frozen) ----------------
__device__ __forceinline__ unsigned pkbf(float lo, float hi2) {
    bf16x2 t; t[0] = (bf16)lo; t[1] = (bf16)hi2;
    return __builtin_bit_cast(unsigned, t);
}

__global__ __launch_bounds__(512, 4)
void attn_fwd(const bf16* __restrict__ Qp, const bf16* __restrict__ Kp,
              const bf16* __restrict__ VT, const int* __restrict__ maskp,
              bf16* __restrict__ ctx) {
    // smem: [0,32K) Kbuf [2buf][2half][4096]; [32K,64K) Vbuf; [64K,68K) madd2; [68K,+64) tflag.
    // Epilogue reuse: [0,32K) Omrg[4][32][64] f32; [32K,+512) Lmrg[4][32] f32.
    __shared__ alignas(16) unsigned char smem[69760];
    bf16* Kbuf = (bf16*)smem;
    bf16* Vbuf = (bf16*)(smem + 32768);
    float* madd2 = (float*)(smem + 65536);
    int* tflag = (int*)(smem + 69632);

    int tid = threadIdx.x;
    int lane = tid & 63, w = tid >> 6;      // 8 waves
    int l31 = lane & 31, hi = lane >> 5;
    int hh = w >> 2, wl = w & 3;            // kv-half, wave-in-half (= q-sub)

    // XCD swizzle: 512 blocks = 8 XCDs x 64; 8 whole heads per XCD.
    int fid = blockIdx.x;
    int xcd = fid & 7, idx = fid >> 3;       // idx 0..63
    int by = xcd * 8 + (idx >> 3);           // head-batch 0..63
    int bx = idx & 7;                        // q-block 0..7
    int b = by >> 4, h = by & 15;
    int q0 = bx * 128;

    // ---- mask precompute: madd2[1024] + per-64-tile flags ----
    {
        madd2[tid] = maskp[b * SEQ + tid] ? 0.f : MASKNEG;
        madd2[512 + tid] = maskp[b * SEQ + 512 + tid] ? 0.f : MASKNEG;
#pragma unroll
        for (int i = 0; i < 2; ++i) {
            int t = w * 2 + i;
            unsigned long long bl = __ballot(maskp[b * SEQ + t * 64 + lane] != 0);
            if (lane == 0) tflag[t] = (bl == ~0ull);
        }
    }

    // Q B-fragments (col=q=lane&31, k-slot ks: d = ks*16 + hi*8 + j); q-sub = wl
    bf16x8 qf[4];
    {
        const bf16* qb = Qp + ((size_t)(b * SEQ + q0 + wl * 32 + l31)) * D_MODEL + h * 64 + hi * 8;
#pragma unroll
        for (int ks = 0; ks < 4; ++ks) qf[ks] = *(const bf16x8*)(qb + ks * 16);
    }

    f32x16 oacc0 = {}, oacc1 = {};
    float lsum = 0.f;

    // stage tile t (0..7) of this wave's half into buf: global tile kt = hh*8 + t
    auto stage = [&](int buf, int t) {
        int kv0 = (hh * 8 + t) * 64;
        bf16* Kd = Kbuf + (size_t)(buf * 2 + hh) * 4096;
        bf16* Vd = Vbuf + (size_t)(buf * 2 + hh) * 4096;
#pragma unroll
        for (int i = 0; i < 2; ++i) {
            int seg = wl * 2 + i;                 // 0..7
            int row = seg * 8 + (lane >> 3);      // 0..63
            int cs = ((lane & 7) ^ (row & 7)) * 8;   // pre-swizzled source chunk
            const bf16* srcK = Kp + ((size_t)(b * SEQ + kv0 + row)) * D_MODEL + h * 64 + cs;
            __builtin_amdgcn_global_load_lds(
                (const __attribute__((address_space(1))) void*)srcK,
                (__attribute__((address_space(3))) void*)(Kd + seg * 512), 16, 0, 0);
            const bf16* srcV = VT + ((size_t)(b * 1024 + h * 64 + row)) * SEQ + kv0 + cs;
            __builtin_amdgcn_global_load_lds(
                (const __attribute__((address_space(1))) void*)srcV,
                (__attribute__((address_space(3))) void*)(Vd + seg * 512), 16, 0, 0);
        }
    };

    // process one 32-kv score chain: exp2+sum, pack, PV (ks = ksb, ksb+1)
    auto half_p = [&](f32x16& p, const float* mbh, int flag, const bf16* Vl, int ksb) -> float {
        float a0 = 0.f, a1 = 0.f, a2 = 0.f, a3 = 0.f;
        if (flag) {
#pragma unroll
            for (int g = 0; g < 4; ++g) {
                float s0 = 0.f;
#pragma unroll
                for (int c = 0; c < 4; ++c) {
                    int r = g * 4 + c;
                    float e = EXP2(p[r]);
                    p[r] = e; s0 += e;
                }
                if (g == 0) a0 = s0; else if (g == 1) a1 = s0;
                else if (g == 2) a2 = s0; else a3 = s0;
            }
        } else {
#pragma unroll
            for (int g = 0; g < 4; ++g) {
                f32x4 mk = *(const f32x4*)(mbh + g * 8 + hi * 4);
                float s0 = 0.f;
#pragma unroll
                for (int c = 0; c < 4; ++c) {
                    int r = g * 4 + c;
                    float e = EXP2(p[r] + mk[c]);
                    p[r] = e; s0 += e;
                }
                if (g == 0) a0 = s0; else if (g == 1) a1 = s0;
                else if (g == 2) a2 = s0; else a3 = s0;
            }
        }
        union FragU { bf16x8 v; unsigned u[4]; };
        FragU A0, A1;
#define PKSW(PV, RA, RB, DST)  { \
            unsigned a_ = pkbf(PV[RA], PV[(RA) + 1]); \
            unsigned b_ = pkbf(PV[RB], PV[(RB) + 1]); \
            auto rr_ = __builtin_amdgcn_permlane32_swap(a_, b_, false, false); \
            DST.u[((RA) & 3) >> 1] = rr_[0]; DST.u[(((RA) & 3) >> 1) + 2] = rr_[1]; }
        PKSW(p, 0, 4,  A0);
        PKSW(p, 2, 6,  A0);
        PKSW(p, 8, 12, A1);
        PKSW(p, 10, 14, A1);
#undef PKSW
        __builtin_amdgcn_s_setprio(1);
#pragma unroll
        for (int i = 0; i < 2; ++i) {
            int ks = ksb + i;
            bf16x8 pav = i ? A1.v : A0.v;
            int sl = ((2 * ks + hi) ^ (l31 & 7)) * 8;
            bf16x8 v0 = *(const bf16x8*)(&Vl[l31 * 64 + sl]);
            bf16x8 v1 = *(const bf16x8*)(&Vl[(32 + l31) * 64 + sl]);
            oacc0 = __builtin_amdgcn_mfma_f32_32x32x16_bf16(pav, v0, oacc0, 0, 0, 0);
            oacc1 = __builtin_amdgcn_mfma_f32_32x32x16_bf16(pav, v1, oacc1, 0, 0, 0);
        }
        __builtin_amdgcn_s_setprio(0);
        return (a0 + a1) + (a2 + a3);
    };

    stage(0, 0);
    __syncthreads();

    for (int t = 0; t < 8; ++t) {
        int cur = t & 1;
        if (t + 1 < 8) stage(cur ^ 1, t + 1);
        int kt = hh * 8 + t;
        const bf16* Kl = Kbuf + (size_t)(cur * 2 + hh) * 4096;
        const bf16* Vl = Vbuf + (size_t)(cur * 2 + hh) * 4096;
        const float* mb = &madd2[kt * 64];
        int flag = tflag[kt];

        float ts;
        {   // chain A: kv rows [0,32) of tile
            f32x16 p = {};
            __builtin_amdgcn_s_setprio(1);
#pragma unroll
            for (int ks = 0; ks < 4; ++ks) {
                int sl = ((2 * ks + hi) ^ (l31 & 7)) * 8;
                bf16x8 k0 = *(const bf16x8*)(&Kl[l31 * 64 + sl]);
                p = __builtin_amdgcn_mfma_f32_32x32x16_bf16(k0, qf[ks], p, 0, 0, 0);
            }
            __builtin_amdgcn_s_setprio(0);
            ts = half_p(p, mb, flag, Vl, 0);
        }
        {   // chain B: kv rows [32,64) of tile
            f32x16 p = {};
            __builtin_amdgcn_s_setprio(1);
#pragma unroll
            for (int ks = 0; ks < 4; ++ks) {
                int sl = ((2 * ks + hi) ^ (l31 & 7)) * 8;
                bf16x8 k1 = *(const bf16x8*)(&Kl[(32 + l31) * 64 + sl]);
                p = __builtin_amdgcn_mfma_f32_32x32x16_bf16(k1, qf[ks], p, 0, 0, 0);
            }
            __builtin_amdgcn_s_setprio(0);
            ts += half_p(p, mb + 32, flag, Vl, 2);
        }
        ts += __shfl_xor(ts, 32);
        lsum += ts;

        __syncthreads();
    }

    // ---- merge halves (exp2-space, no max => pure addition), then normalize+store ----
    float* Omrg = (float*)smem;              // [4][32][64]
    float* Lmrg = (float*)(smem + 32768);    // [4][32]
    if (hh == 1) {
#pragma unroll
        for (int g = 0; g < 4; ++g) {
#pragma unroll
            for (int c = 0; c < 4; ++c) {
                int r = g * 4 + c;
                int q = c + g * 8 + hi * 4;      // q-row within sub-tile
                Omrg[wl * 2048 + q * 64 + l31]      = oacc0[r];
                Omrg[wl * 2048 + q * 64 + 32 + l31] = oacc1[r];
            }
        }
        if (hi == 0) Lmrg[wl * 32 + l31] = lsum;
    }
    __syncthreads();
    if (hh == 0) {
        float ltot = lsum + Lmrg[wl * 32 + l31];   // lane l31 holds q=l31's denom
#pragma unroll
        for (int g = 0; g < 4; ++g) {
#pragma unroll
            for (int c = 0; c < 4; ++c) {
                int r = g * 4 + c;
                int q = c + g * 8 + hi * 4;
                float o0 = oacc0[r] + Omrg[wl * 2048 + q * 64 + l31];
                float o1 = oacc1[r] + Omrg[wl * 2048 + q * 64 + 32 + l31];
                float sden = __shfl(ltot, q);
                float inv = 1.0f / sden;
                int qg = q0 + wl * 32 + q;
                size_t base = ((size_t)(b * SEQ + qg)) * D_MODEL + h * 64;
                ctx[base + l31]      = (bf16)(o0 * inv);
                ctx[base + 32 + l31] = (bf16)(o1 * inv);
            }
        }
    }
}

// ---------------- launch ----------------
extern "C" void kernel_launch(void* const* d_in, const int* in_sizes, int n_in,
                              void* d_out, int out_size, void* d_ws, size_t ws_size,
                              hipStream_t stream) {
    const float* q  = (const float*)d_in[0];
    const float* k  = (const float*)d_in[1];
    const float* v  = (const float*)d_in[2];
    const int* mask = (const int*)d_in[3];
    const float* Wq = (const float*)d_in[4];
    const float* bq = (const float*)d_in[5];
    const float* Wk = (const float*)d_in[6];
    const float* bk = (const float*)d_in[7];
    const float* Wv = (const float*)d_in[8];
    const float* bv = (const float*)d_in[9];
    const float* Wo = (const float*)d_in[10];
    const float* bo = (const float*)d_in[11];
    float* out = (float*)d_out;

    char* ws = (char*)d_ws;
    size_t szQKV = (size_t)MTOT * D_MODEL * sizeof(bf16);   // 8 MB
    size_t szW = (size_t)D_MODEL * D_MODEL * sizeof(bf16);  // 2 MB
    bf16* qb  = (bf16*)ws; ws += szQKV;
    bf16* kb  = (bf16*)ws; ws += szQKV;
    bf16* vb  = (bf16*)ws; ws += szQKV;
    bf16* Wqb = (bf16*)ws; ws += szW;
    bf16* Wkb = (bf16*)ws; ws += szW;
    bf16* Wvb = (bf16*)ws; ws += szW;
    bf16* Wob = (bf16*)ws; ws += szW;
    bf16* Qp  = (bf16*)ws; ws += szQKV;
    bf16* Kp  = (bf16*)ws; ws += szQKV;
    bf16* VT  = (bf16*)ws; ws += szQKV;   // transposed V: [B][H][64][SEQ]
    bf16* ctx = (bf16*)ws; ws += szQKV;

    dim3 gc(512, 7, 1);
    cast_all<<<gc, 256, 0, stream>>>(q, k, v, Wq, Wk, Wv, Wo,
                                     qb, kb, vb, Wqb, Wkb, Wvb, Wob);

    dim3 g1(MTOT / 128, D_MODEL / 128, 3);
    gemm_bt<bf16, 0><<<g1, 256, 0, stream>>>(qb, kb, vb, Wqb, Wkb, Wvb,
                                             bq, bk, bv, Qp, Kp, VT);

    attn_fwd<<<dim3(512), 512, 0, stream>>>(Qp, Kp, VT, mask, ctx);

    dim3 g3(MTOT / 128, D_MODEL / 128, 1);
    gemm_bt<float, 1><<<g3, 256, 0, stream>>>(ctx, ctx, ctx, Wob, Wob, Wob,
                                              bo, bo, bo, out, out, out);
}

// Round 13
// 106.166 us; speedup vs baseline: 1.5614x; 1.5614x over previous
//
#include <hip/hip_runtime.h>
#include <hip/hip_bf16.h>
#include <math.h>

typedef __bf16 bf16;
typedef __bf16 bf16x8 __attribute__((ext_vector_type(8)));
typedef __bf16 bf16x2 __attribute__((ext_vector_type(2)));
typedef float f32x4 __attribute__((ext_vector_type(4)));
typedef float f32x16 __attribute__((ext_vector_type(16)));

#define D_MODEL 1024
#define SEQ 1024
#define BATCH 4
#define NHEAD 16
#define MTOT (BATCH*SEQ)   // 4096

#define QSCALE 0.18033688011112042f
#define MASKNEG -1e9f
#define EXP2(x) __builtin_amdgcn_exp2f(x)

#define GLL(SRC, DST) __builtin_amdgcn_global_load_lds( \
    (const __attribute__((address_space(1))) void*)(SRC), \
    (__attribute__((address_space(3))) void*)(DST), 16, 0, 0)

// ---------------- fused f32 -> bf16 casts (7 tensors, one launch; BW-roofline) ----------------
__global__ void cast_all(const float* __restrict__ s0, const float* __restrict__ s1,
                         const float* __restrict__ s2, const float* __restrict__ s3,
                         const float* __restrict__ s4, const float* __restrict__ s5,
                         const float* __restrict__ s6,
                         bf16* d0, bf16* d1, bf16* d2, bf16* d3, bf16* d4, bf16* d5, bf16* d6) {
    int z = blockIdx.y;
    const float* s; bf16* d; int n;
    switch (z) {
        case 0: s = s0; d = d0; n = MTOT * D_MODEL; break;
        case 1: s = s1; d = d1; n = MTOT * D_MODEL; break;
        case 2: s = s2; d = d2; n = MTOT * D_MODEL; break;
        case 3: s = s3; d = d3; n = D_MODEL * D_MODEL; break;
        case 4: s = s4; d = d4; n = D_MODEL * D_MODEL; break;
        case 5: s = s5; d = d5; n = D_MODEL * D_MODEL; break;
        default: s = s6; d = d6; n = D_MODEL * D_MODEL; break;
    }
    int idx = (blockIdx.x * blockDim.x + threadIdx.x) * 8;
    int stride = gridDim.x * blockDim.x * 8;
    for (int i = idx; i < n; i += stride) {
        const float4* p = (const float4*)(s + i);
        float4 a = p[0], b = p[1];
        bf16x8 o;
        o[0] = (bf16)a.x; o[1] = (bf16)a.y; o[2] = (bf16)a.z; o[3] = (bf16)a.w;
        o[4] = (bf16)b.x; o[5] = (bf16)b.y; o[6] = (bf16)b.z; o[7] = (bf16)b.w;
        *(bf16x8*)(d + i) = o;
    }
}

// ---------------- QKV GEMM: 8-phase 256x256 template (T2+T3+T4+T5) ----------------
// BM=BN=256, BK=64, 8 waves (wm=w>>2 in {0,1}, wn=w&3 in {0..3}), 512 threads.
// INTERLEAVED wave->row mapping: wave wm's m-frag j sits at tile rows (2j+wm)*16, so
// m-frags 0-3 (all waves) live in A-half0 (rows 0-127), 4-7 in A-half1; B likewise
// with (4n+wn)*16. Quadrant Q(M,N) therefore reads exactly {A-half-M, B-half-N}.
// LDS: 2 bufs x 2 halves x [128 rows][64 bf16] per tensor = 128 KiB. Rows are 128B ->
// T2 XOR swizzle chunk' = chunk ^ (row&7), realized as pre-swizzled global source +
// linear global_load_lds (rule #21) and XOR on the ds_read side.
// Schedule per iteration (tiles t0=2i->buf0, t1=2i+1->buf1; s0=2i+2, s1=2i+3):
//   ph1: rd A0b0+B0b0, stage A1(t1);  ph2: rd B1b0, stage B1(t1)
//   ph3: rd A1b0, stage A0(s0);       ph4: -, stage B0(s0)
//   ph5: rd A0b1+B0b1, stage A1(s0);  ph6: rd B1b1, stage B1(s0)
//   ph7: rd A1b1, stage A0(s1);       ph8: -, stage B0(s1)
// Race ledger: every stage targets a region whose last ds_read is >=2 phases prior
// (reads drained by that phase's lgkmcnt(0) + barrier); every staged half is first
// read >=4 stage-ops later => per-phase vmcnt(6) (3 half-tiles in flight) + barrier
// guarantees landing. Prologue = 6 half-tiles: T0{A0,B0,A1,B1} + T1{A0,B0}.
#define VMBAR  do { asm volatile("s_waitcnt vmcnt(6)" ::: "memory"); \
                    __builtin_amdgcn_s_barrier(); \
                    __builtin_amdgcn_sched_barrier(0); } while (0)
#define LGKM0  do { asm volatile("s_waitcnt lgkmcnt(0)" ::: "memory"); \
                    __builtin_amdgcn_sched_barrier(0); } while (0)

__global__ __launch_bounds__(512, 2)
void gemm_qkv8(const bf16* __restrict__ A0p, const bf16* __restrict__ A1p, const bf16* __restrict__ A2p,
               const bf16* __restrict__ W0, const bf16* __restrict__ W1, const bf16* __restrict__ W2,
               const float* __restrict__ bias0, const float* __restrict__ bias1, const float* __restrict__ bias2,
               bf16* __restrict__ O0, bf16* __restrict__ O1, bf16* __restrict__ O2) {
    constexpr int K = D_MODEL;
    __shared__ bf16 Al[2][2][8192];   // [buf][half][row*64 + chunk*8], 64 KB
    __shared__ bf16 Bl[2][2][8192];   // 64 KB

    int z = blockIdx.z;
    const bf16* A = (z == 0) ? A0p : (z == 1) ? A1p : A2p;
    const bf16* W = (z == 0) ? W0 : (z == 1) ? W1 : W2;
    const float* bias = (z == 0) ? bias0 : (z == 1) ? bias1 : bias2;
    bf16* Out = (z == 0) ? O0 : (z == 1) ? O1 : O2;

    int tid = threadIdx.x;
    int l = tid & 63, w = tid >> 6;
    int l15 = l & 15, l4 = l >> 4;
    int wm = w >> 2, wn = w & 3;
    int m0 = blockIdx.x * 256;
    int n0 = blockIdx.y * 256;

    f32x4 acc[8][4] = {};

    // staging: thread (w,l), load j in {0,1}: LDS row r=(w*2+j)*8+(l>>3), chunk'=l&7;
    // source chunk c = chunk' ^ (r&7) = (l&7)^((l>>3)&7)  [pre-swizzled source]
    int srf = l >> 3;                       // 0..7
    int scc = (l & 7) ^ (srf & 7);          // swizzled source chunk

    auto stageA = [&](int buf, int H, int kt) {
#pragma unroll
        for (int j = 0; j < 2; ++j) {
            int r = (w * 2 + j) * 8 + srf;
            const bf16* src = A + (size_t)(m0 + H * 128 + r) * K + kt * 64 + scc * 8;
            GLL(src, &Al[buf][H][(w * 2 + j) * 512]);
        }
    };
    auto stageB = [&](int buf, int H, int kt) {
#pragma unroll
        for (int j = 0; j < 2; ++j) {
            int r = (w * 2 + j) * 8 + srf;
            const bf16* src = W + (size_t)(n0 + H * 128 + r) * K + kt * 64 + scc * 8;
            GLL(src, &Bl[buf][H][(w * 2 + j) * 512]);
        }
    };

    bf16x8 a[4][2], bf0[2][2], bf1[2][2];

    // frag reads (swizzled): row-in-half rh, chunk' = (ks*4+l4) ^ (rh&7); rh&7 == l15&7
    auto loadA = [&](int buf, int H) {
#pragma unroll
        for (int j2 = 0; j2 < 4; ++j2) {
            int rh = (2 * j2 + wm) * 16 + l15;
#pragma unroll
            for (int ks = 0; ks < 2; ++ks) {
                int cp = (ks * 4 + l4) ^ (l15 & 7);
                a[j2][ks] = *(const bf16x8*)&Al[buf][H][rh * 64 + cp * 8];
            }
        }
    };
    auto loadB = [&](bf16x8 bdst[2][2], int buf, int H) {
#pragma unroll
        for (int n2 = 0; n2 < 2; ++n2) {
            int rh = (4 * n2 + wn) * 16 + l15;
#pragma unroll
            for (int ks = 0; ks < 2; ++ks) {
                int cp = (ks * 4 + l4) ^ (l15 & 7);
                bdst[n2][ks] = *(const bf16x8*)&Bl[buf][H][rh * 64 + cp * 8];
            }
        }
    };

#define MMAQ(M, N, BSET) do { \
        __builtin_amdgcn_s_setprio(1); \
        _Pragma("unroll") \
        for (int j2 = 0; j2 < 4; ++j2) \
        _Pragma("unroll") \
        for (int n2 = 0; n2 < 2; ++n2) \
        _Pragma("unroll") \
        for (int ks = 0; ks < 2; ++ks) \
            acc[(M)*4 + j2][(N)*2 + n2] = __builtin_amdgcn_mfma_f32_16x16x32_bf16( \
                a[j2][ks], BSET[n2][ks], acc[(M)*4 + j2][(N)*2 + n2], 0, 0, 0); \
        __builtin_amdgcn_s_setprio(0); \
    } while (0)

    // prologue: 6 half-tiles (12 loads)
    stageA(0, 0, 0); stageB(0, 0, 0);
    stageA(0, 1, 0); stageB(0, 1, 0);
    stageA(1, 0, 1); stageB(1, 0, 1);

#pragma unroll 1
    for (int i = 0; i < 8; ++i) {
        int t1 = 2 * i + 1, s0 = 2 * i + 2, s1 = 2 * i + 3;
        bool pre = (i < 7);
        // ph1
        VMBAR;
        loadA(0, 0); loadB(bf0, 0, 0);
        stageA(1, 1, t1);
        LGKM0; MMAQ(0, 0, bf0);
        // ph2
        VMBAR;
        loadB(bf1, 0, 1);
        stageB(1, 1, t1);
        LGKM0; MMAQ(0, 1, bf1);
        // ph3
        VMBAR;
        loadA(0, 1);
        if (pre) stageA(0, 0, s0);
        LGKM0; MMAQ(1, 0, bf0);
        // ph4
        VMBAR;
        if (pre) stageB(0, 0, s0);
        MMAQ(1, 1, bf1);
        // ph5
        VMBAR;
        loadA(1, 0); loadB(bf0, 1, 0);
        if (pre) stageA(0, 1, s0);
        LGKM0; MMAQ(0, 0, bf0);
        // ph6
        VMBAR;
        loadB(bf1, 1, 1);
        if (pre) stageB(0, 1, s0);
        LGKM0; MMAQ(0, 1, bf1);
        // ph7
        VMBAR;
        loadA(1, 1);
        if (pre) stageA(1, 0, s1);
        LGKM0; MMAQ(1, 0, bf0);
        // ph8
        VMBAR;
        if (pre) stageB(1, 0, s1);
        MMAQ(1, 1, bf1);
    }
#undef MMAQ

    // epilogue
    float bload[4];
#pragma unroll
    for (int n = 0; n < 4; ++n) bload[n] = bias[n0 + (4 * n + wn) * 16 + l15];

    if (z == 2) {
        // V stored transposed: VT[(b*1024 + col)*1024 + s]
#pragma unroll
        for (int j = 0; j < 8; ++j) {
            int row = m0 + (2 * j + wm) * 16 + l4 * 4;
#pragma unroll
            for (int n = 0; n < 4; ++n) {
                int col = n0 + (4 * n + wn) * 16 + l15;
                float bl = bload[n];
#pragma unroll
                for (int r = 0; r < 4; ++r) {
                    float vv = acc[j][n][r] + bl;
                    int rr = row + r;
                    int bb = rr >> 10, s = rr & 1023;
                    Out[((size_t)(bb * 1024 + col)) * 1024 + s] = (bf16)vv;
                }
            }
        }
    } else {
        const float sc = (z == 0) ? QSCALE : 1.0f;
#pragma unroll
        for (int j = 0; j < 8; ++j) {
            int row = m0 + (2 * j + wm) * 16 + l4 * 4;
#pragma unroll
            for (int n = 0; n < 4; ++n) {
                int col = n0 + (4 * n + wn) * 16 + l15;
                float bl = bload[n];
#pragma unroll
                for (int r = 0; r < 4; ++r) {
                    float vv = (acc[j][n][r] + bl) * sc;
                    Out[(size_t)(row + r) * D_MODEL + col] = (bf16)vv;
                }
            }
        }
    }
}

// ---------------- Output projection GEMM (proven R9 2-phase 128x128): out = ctx @ Wo^T + bo ----------------
__global__ __launch_bounds__(256, 3)
void gemm_out(const bf16* __restrict__ A, const bf16* __restrict__ W,
              const float* __restrict__ bias, float* __restrict__ Out) {
    constexpr int BK = 32;
    constexpr int K = D_MODEL;
    constexpr int NT = K / BK;
    __shared__ alignas(16) bf16 As[2][128 * BK];
    __shared__ alignas(16) bf16 Bs[2][128 * BK];

    int tid = threadIdx.x;
    int lane = tid & 63, w = tid >> 6;
    int l15 = lane & 15, l4 = lane >> 4;
    int m0 = blockIdx.x * 128;
    int n0 = blockIdx.y * 128;
    int wm = w >> 1, wn = w & 1;

    f32x4 acc[4][4] = {};
    int srow = lane >> 2;
    int scol = (lane & 3) * 8;

    auto stage = [&](int buf, int kt) {
#pragma unroll
        for (int i = 0; i < 2; ++i) {
            int seg = w * 2 + i;
            int row = seg * 16 + srow;
            const bf16* srcA = A + (size_t)(m0 + row) * K + kt * BK + scol;
            const bf16* srcB = W + (size_t)(n0 + row) * K + kt * BK + scol;
            GLL(srcA, &As[buf][seg * 512]);
            GLL(srcB, &Bs[buf][seg * 512]);
        }
    };

    stage(0, 0);
    __syncthreads();

    for (int kt = 0; kt < NT; ++kt) {
        int cur = kt & 1;
        if (kt + 1 < NT) stage(cur ^ 1, kt + 1);

        const bf16* pa = &As[cur][(wm * 64 + l15) * BK + l4 * 8];
        const bf16* pb = &Bs[cur][(wn * 64 + l15) * BK + l4 * 8];
        bf16x8 af[4], bv[4];
#pragma unroll
        for (int m = 0; m < 4; ++m) af[m] = *(const bf16x8*)(pa + m * 16 * BK);
#pragma unroll
        for (int n = 0; n < 4; ++n) bv[n] = *(const bf16x8*)(pb + n * 16 * BK);
#pragma unroll
        for (int m = 0; m < 4; ++m)
#pragma unroll
            for (int n = 0; n < 4; ++n)
                acc[m][n] = __builtin_amdgcn_mfma_f32_16x16x32_bf16(af[m], bv[n], acc[m][n], 0, 0, 0);

        __syncthreads();
    }

    float bload[4];
#pragma unroll
    for (int n = 0; n < 4; ++n) bload[n] = bias[n0 + wn * 64 + n * 16 + l15];
#pragma unroll
    for (int m = 0; m < 4; ++m) {
        int row = m0 + wm * 64 + m * 16 + l4 * 4;
#pragma unroll
        for (int n = 0; n < 4; ++n) {
            int col = n0 + wn * 64 + n * 16 + l15;
            float bl = bload[n];
#pragma unroll
            for (int r = 0; r < 4; ++r)
                Out[(size_t)(row + r) * D_MODEL + col] = acc[m][n][r] + bl;
        }
    }
}

// ---------------- Flash attention fwd: intra-block split-KV, 8 waves, LOW-VGPR (R9, frozen) ----------------
__device__ __forceinline__ unsigned pkbf(float lo, float hi2) {
    bf16x2 t; t[0] = (bf16)lo; t[1] = (bf16)hi2;
    return __builtin_bit_cast(unsigned, t);
}

__global__ __launch_bounds__(512, 4)
void attn_fwd(const bf16* __restrict__ Qp, const bf16* __restrict__ Kp,
              const bf16* __restrict__ VT, const int* __restrict__ maskp,
              bf16* __restrict__ ctx) {
    __shared__ alignas(16) unsigned char smem[69760];
    bf16* Kbuf = (bf16*)smem;
    bf16* Vbuf = (bf16*)(smem + 32768);
    float* madd2 = (float*)(smem + 65536);
    int* tflag = (int*)(smem + 69632);

    int tid = threadIdx.x;
    int lane = tid & 63, w = tid >> 6;      // 8 waves
    int l31 = lane & 31, hi = lane >> 5;
    int hh = w >> 2, wl = w & 3;            // kv-half, wave-in-half (= q-sub)

    int fid = blockIdx.x;
    int xcd = fid & 7, idx = fid >> 3;
    int by = xcd * 8 + (idx >> 3);
    int bx = idx & 7;
    int b = by >> 4, h = by & 15;
    int q0 = bx * 128;

    {
        madd2[tid] = maskp[b * SEQ + tid] ? 0.f : MASKNEG;
        madd2[512 + tid] = maskp[b * SEQ + 512 + tid] ? 0.f : MASKNEG;
#pragma unroll
        for (int i = 0; i < 2; ++i) {
            int t = w * 2 + i;
            unsigned long long bl = __ballot(maskp[b * SEQ + t * 64 + lane] != 0);
            if (lane == 0) tflag[t] = (bl == ~0ull);
        }
    }

    bf16x8 qf[4];
    {
        const bf16* qb = Qp + ((size_t)(b * SEQ + q0 + wl * 32 + l31)) * D_MODEL + h * 64 + hi * 8;
#pragma unroll
        for (int ks = 0; ks < 4; ++ks) qf[ks] = *(const bf16x8*)(qb + ks * 16);
    }

    f32x16 oacc0 = {}, oacc1 = {};
    float lsum = 0.f;

    auto stage = [&](int buf, int t) {
        int kv0 = (hh * 8 + t) * 64;
        bf16* Kd = Kbuf + (size_t)(buf * 2 + hh) * 4096;
        bf16* Vd = Vbuf + (size_t)(buf * 2 + hh) * 4096;
#pragma unroll
        for (int i = 0; i < 2; ++i) {
            int seg = wl * 2 + i;
            int row = seg * 8 + (lane >> 3);
            int cs = ((lane & 7) ^ (row & 7)) * 8;
            const bf16* srcK = Kp + ((size_t)(b * SEQ + kv0 + row)) * D_MODEL + h * 64 + cs;
            GLL(srcK, Kd + seg * 512);
            const bf16* srcV = VT + ((size_t)(b * 1024 + h * 64 + row)) * SEQ + kv0 + cs;
            GLL(srcV, Vd + seg * 512);
        }
    };

    auto half_p = [&](f32x16& p, const float* mbh, int flag, const bf16* Vl, int ksb) -> float {
        float a0 = 0.f, a1 = 0.f, a2 = 0.f, a3 = 0.f;
        if (flag) {
#pragma unroll
            for (int g = 0; g < 4; ++g) {
                float s0 = 0.f;
#pragma unroll
                for (int c = 0; c < 4; ++c) {
                    int r = g * 4 + c;
                    float e = EXP2(p[r]);
                    p[r] = e; s0 += e;
                }
                if (g == 0) a0 = s0; else if (g == 1) a1 = s0;
                else if (g == 2) a2 = s0; else a3 = s0;
            }
        } else {
#pragma unroll
            for (int g = 0; g < 4; ++g) {
                f32x4 mk = *(const f32x4*)(mbh + g * 8 + hi * 4);
                float s0 = 0.f;
#pragma unroll
                for (int c = 0; c < 4; ++c) {
                    int r = g * 4 + c;
                    float e = EXP2(p[r] + mk[c]);
                    p[r] = e; s0 += e;
                }
                if (g == 0) a0 = s0; else if (g == 1) a1 = s0;
                else if (g == 2) a2 = s0; else a3 = s0;
            }
        }
        union FragU { bf16x8 v; unsigned u[4]; };
        FragU A0, A1;
#define PKSW(PV, RA, RB, DST)  { \
            unsigned a_ = pkbf(PV[RA], PV[(RA) + 1]); \
            unsigned b_ = pkbf(PV[RB], PV[(RB) + 1]); \
            auto rr_ = __builtin_amdgcn_permlane32_swap(a_, b_, false, false); \
            DST.u[((RA) & 3) >> 1] = rr_[0]; DST.u[(((RA) & 3) >> 1) + 2] = rr_[1]; }
        PKSW(p, 0, 4,  A0);
        PKSW(p, 2, 6,  A0);
        PKSW(p, 8, 12, A1);
        PKSW(p, 10, 14, A1);
#undef PKSW
        __builtin_amdgcn_s_setprio(1);
#pragma unroll
        for (int i = 0; i < 2; ++i) {
            int ks = ksb + i;
            bf16x8 pav = i ? A1.v : A0.v;
            int sl = ((2 * ks + hi) ^ (l31 & 7)) * 8;
            bf16x8 v0 = *(const bf16x8*)(&Vl[l31 * 64 + sl]);
            bf16x8 v1 = *(const bf16x8*)(&Vl[(32 + l31) * 64 + sl]);
            oacc0 = __builtin_amdgcn_mfma_f32_32x32x16_bf16(pav, v0, oacc0, 0, 0, 0);
            oacc1 = __builtin_amdgcn_mfma_f32_32x32x16_bf16(pav, v1, oacc1, 0, 0, 0);
        }
        __builtin_amdgcn_s_setprio(0);
        return (a0 + a1) + (a2 + a3);
    };

    stage(0, 0);
    __syncthreads();

    for (int t = 0; t < 8; ++t) {
        int cur = t & 1;
        if (t + 1 < 8) stage(cur ^ 1, t + 1);
        int kt = hh * 8 + t;
        const bf16* Kl = Kbuf + (size_t)(cur * 2 + hh) * 4096;
        const bf16* Vl = Vbuf + (size_t)(cur * 2 + hh) * 4096;
        const float* mb = &madd2[kt * 64];
        int flag = tflag[kt];

        float ts;
        {
            f32x16 p = {};
            __builtin_amdgcn_s_setprio(1);
#pragma unroll
            for (int ks = 0; ks < 4; ++ks) {
                int sl = ((2 * ks + hi) ^ (l31 & 7)) * 8;
                bf16x8 k0 = *(const bf16x8*)(&Kl[l31 * 64 + sl]);
                p = __builtin_amdgcn_mfma_f32_32x32x16_bf16(k0, qf[ks], p, 0, 0, 0);
            }
            __builtin_amdgcn_s_setprio(0);
            ts = half_p(p, mb, flag, Vl, 0);
        }
        {
            f32x16 p = {};
            __builtin_amdgcn_s_setprio(1);
#pragma unroll
            for (int ks = 0; ks < 4; ++ks) {
                int sl = ((2 * ks + hi) ^ (l31 & 7)) * 8;
                bf16x8 k1 = *(const bf16x8*)(&Kl[(32 + l31) * 64 + sl]);
                p = __builtin_amdgcn_mfma_f32_32x32x16_bf16(k1, qf[ks], p, 0, 0, 0);
            }
            __builtin_amdgcn_s_setprio(0);
            ts += half_p(p, mb + 32, flag, Vl, 2);
        }
        ts += __shfl_xor(ts, 32);
        lsum += ts;

        __syncthreads();
    }

    float* Omrg = (float*)smem;
    float* Lmrg = (float*)(smem + 32768);
    if (hh == 1) {
#pragma unroll
        for (int g = 0; g < 4; ++g) {
#pragma unroll
            for (int c = 0; c < 4; ++c) {
                int r = g * 4 + c;
                int q = c + g * 8 + hi * 4;
                Omrg[wl * 2048 + q * 64 + l31]      = oacc0[r];
                Omrg[wl * 2048 + q * 64 + 32 + l31] = oacc1[r];
            }
        }
        if (hi == 0) Lmrg[wl * 32 + l31] = lsum;
    }
    __syncthreads();
    if (hh == 0) {
        float ltot = lsum + Lmrg[wl * 32 + l31];
#pragma unroll
        for (int g = 0; g < 4; ++g) {
#pragma unroll
            for (int c = 0; c < 4; ++c) {
                int r = g * 4 + c;
                int q = c + g * 8 + hi * 4;
                float o0 = oacc0[r] + Omrg[wl * 2048 + q * 64 + l31];
                float o1 = oacc1[r] + Omrg[wl * 2048 + q * 64 + 32 + l31];
                float sden = __shfl(ltot, q);
                float inv = 1.0f / sden;
                int qg = q0 + wl * 32 + q;
                size_t base = ((size_t)(b * SEQ + qg)) * D_MODEL + h * 64;
                ctx[base + l31]      = (bf16)(o0 * inv);
                ctx[base + 32 + l31] = (bf16)(o1 * inv);
            }
        }
    }
}

// ---------------- launch ----------------
extern "C" void kernel_launch(void* const* d_in, const int* in_sizes, int n_in,
                              void* d_out, int out_size, void* d_ws, size_t ws_size,
                              hipStream_t stream) {
    const float* q  = (const float*)d_in[0];
    const float* k  = (const float*)d_in[1];
    const float* v  = (const float*)d_in[2];
    const int* mask = (const int*)d_in[3];
    const float* Wq = (const float*)d_in[4];
    const float* bq = (const float*)d_in[5];
    const float* Wk = (const float*)d_in[6];
    const float* bk = (const float*)d_in[7];
    const float* Wv = (const float*)d_in[8];
    const float* bv = (const float*)d_in[9];
    const float* Wo = (const float*)d_in[10];
    const float* bo = (const float*)d_in[11];
    float* out = (float*)d_out;

    char* ws = (char*)d_ws;
    size_t szQKV = (size_t)MTOT * D_MODEL * sizeof(bf16);   // 8 MB
    size_t szW = (size_t)D_MODEL * D_MODEL * sizeof(bf16);  // 2 MB
    bf16* qb  = (bf16*)ws; ws += szQKV;
    bf16* kb  = (bf16*)ws; ws += szQKV;
    bf16* vb  = (bf16*)ws; ws += szQKV;
    bf16* Wqb = (bf16*)ws; ws += szW;
    bf16* Wkb = (bf16*)ws; ws += szW;
    bf16* Wvb = (bf16*)ws; ws += szW;
    bf16* Wob = (bf16*)ws; ws += szW;
    bf16* Qp  = (bf16*)ws; ws += szQKV;
    bf16* Kp  = (bf16*)ws; ws += szQKV;
    bf16* VT  = (bf16*)ws; ws += szQKV;   // transposed V: [B][H][64][SEQ]
    bf16* ctx = (bf16*)ws; ws += szQKV;

    dim3 gc(512, 7, 1);
    cast_all<<<gc, 256, 0, stream>>>(q, k, v, Wq, Wk, Wv, Wo,
                                     qb, kb, vb, Wqb, Wkb, Wvb, Wob);

    dim3 g1(MTOT / 256, D_MODEL / 256, 3);   // 16 x 4 x 3 = 192 blocks
    gemm_qkv8<<<g1, 512, 0, stream>>>(qb, kb, vb, Wqb, Wkb, Wvb,
                                      bq, bk, bv, Qp, Kp, VT);

    attn_fwd<<<dim3(512), 512, 0, stream>>>(Qp, Kp, VT, mask, ctx);

    dim3 g3(MTOT / 128, D_MODEL / 128, 1);
    gemm_out<<<g3, 256, 0, stream>>>(ctx, Wob, bo, out);
}

// Round 14
// 104.220 us; speedup vs baseline: 1.5906x; 1.0187x over previous
//
#include <hip/hip_runtime.h>
#include <hip/hip_bf16.h>
#include <math.h>

typedef __bf16 bf16;
typedef __bf16 bf16x8 __attribute__((ext_vector_type(8)));
typedef __bf16 bf16x2 __attribute__((ext_vector_type(2)));
typedef float f32x4 __attribute__((ext_vector_type(4)));
typedef float f32x16 __attribute__((ext_vector_type(16)));

#define D_MODEL 1024
#define SEQ 1024
#define BATCH 4
#define NHEAD 16
#define MTOT (BATCH*SEQ)   // 4096

// scores computed in exp2-space: fold 1/sqrt(64) * log2(e) into Q projection
#define QSCALE 0.18033688011112042f
#define MASKNEG -1e9f
#define EXP2(x) __builtin_amdgcn_exp2f(x)

#define GLL(SRC, DST) __builtin_amdgcn_global_load_lds( \
    (const __attribute__((address_space(1))) void*)(SRC), \
    (__attribute__((address_space(3))) void*)(DST), 16, 0, 0)

// ---------------- fused f32 -> bf16 casts (7 tensors, one launch; BW-roofline) ----------------
__global__ void cast_all(const float* __restrict__ s0, const float* __restrict__ s1,
                         const float* __restrict__ s2, const float* __restrict__ s3,
                         const float* __restrict__ s4, const float* __restrict__ s5,
                         const float* __restrict__ s6,
                         bf16* d0, bf16* d1, bf16* d2, bf16* d3, bf16* d4, bf16* d5, bf16* d6) {
    int z = blockIdx.y;
    const float* s; bf16* d; int n;
    switch (z) {
        case 0: s = s0; d = d0; n = MTOT * D_MODEL; break;
        case 1: s = s1; d = d1; n = MTOT * D_MODEL; break;
        case 2: s = s2; d = d2; n = MTOT * D_MODEL; break;
        case 3: s = s3; d = d3; n = D_MODEL * D_MODEL; break;
        case 4: s = s4; d = d4; n = D_MODEL * D_MODEL; break;
        case 5: s = s5; d = d5; n = D_MODEL * D_MODEL; break;
        default: s = s6; d = d6; n = D_MODEL * D_MODEL; break;
    }
    int idx = (blockIdx.x * blockDim.x + threadIdx.x) * 8;
    int stride = gridDim.x * blockDim.x * 8;
    for (int i = idx; i < n; i += stride) {
        const float4* p = (const float4*)(s + i);
        float4 a = p[0], b = p[1];
        bf16x8 o;
        o[0] = (bf16)a.x; o[1] = (bf16)a.y; o[2] = (bf16)a.z; o[3] = (bf16)a.w;
        o[4] = (bf16)b.x; o[5] = (bf16)b.y; o[6] = (bf16)b.z; o[7] = (bf16)b.w;
        *(bf16x8*)(d + i) = o;
    }
}

// ---------------- GEMM: C[M,N] = A[M,K] @ W[N,K]^T + bias (R11 proven: 43.2/13.6 us) ----------------
// 3-buffer LDS, prefetch distance 2, counted vmcnt: stage(kt+2) -> compute(kt) ->
// s_waitcnt vmcnt(4) -> raw s_barrier. Buffer rotation mod 3 => race-free.
template<typename OT, int MODE>
__global__ __launch_bounds__(256, 3)
void gemm_bt(const bf16* __restrict__ A0, const bf16* __restrict__ A1, const bf16* __restrict__ A2,
             const bf16* __restrict__ W0, const bf16* __restrict__ W1, const bf16* __restrict__ W2,
             const float* __restrict__ bias0, const float* __restrict__ bias1, const float* __restrict__ bias2,
             OT* __restrict__ O0, OT* __restrict__ O1, OT* __restrict__ O2) {
    constexpr int BK = 32;
    constexpr int K = D_MODEL;
    constexpr int NT = K / BK;   // 32
    __shared__ alignas(16) bf16 As[3][128 * BK];
    __shared__ alignas(16) bf16 Bs[3][128 * BK];

    int z = (MODE == 0) ? blockIdx.z : 0;
    const bf16* A = (z == 0) ? A0 : (z == 1) ? A1 : A2;
    const bf16* W = (z == 0) ? W0 : (z == 1) ? W1 : W2;
    const float* bias = (z == 0) ? bias0 : (z == 1) ? bias1 : bias2;
    OT* Out = (z == 0) ? O0 : (z == 1) ? O1 : O2;

    int tid = threadIdx.x;
    int lane = tid & 63, w = tid >> 6;
    int l15 = lane & 15, l4 = lane >> 4;
    int m0 = blockIdx.x * 128;
    int n0 = blockIdx.y * 128;
    int wm = w >> 1, wn = w & 1;

    f32x4 acc[4][4] = {};

    int srow = lane >> 2;
    int scol = (lane & 3) * 8;

    auto stage = [&](int buf, int kt) {
#pragma unroll
        for (int i = 0; i < 2; ++i) {
            int seg = w * 2 + i;
            int row = seg * 16 + srow;
            const bf16* srcA = A + (size_t)(m0 + row) * K + kt * BK + scol;
            const bf16* srcB = W + (size_t)(n0 + row) * K + kt * BK + scol;
            GLL(srcA, &As[buf][seg * 512]);
            GLL(srcB, &Bs[buf][seg * 512]);
        }
    };

    stage(0, 0);
    stage(1, 1);
    asm volatile("s_waitcnt vmcnt(4)" ::: "memory");
    __builtin_amdgcn_s_barrier();
    __builtin_amdgcn_sched_barrier(0);

    for (int kt = 0; kt < NT; ++kt) {
        int cur = kt - (kt / 3) * 3;           // kt % 3
        if (kt + 2 < NT) stage(kt + 2 - ((kt + 2) / 3) * 3, kt + 2);

        const bf16* pa = &As[cur][(wm * 64 + l15) * BK + l4 * 8];
        const bf16* pb = &Bs[cur][(wn * 64 + l15) * BK + l4 * 8];
        bf16x8 af[4], bv[4];
#pragma unroll
        for (int m = 0; m < 4; ++m) af[m] = *(const bf16x8*)(pa + m * 16 * BK);
#pragma unroll
        for (int n = 0; n < 4; ++n) bv[n] = *(const bf16x8*)(pb + n * 16 * BK);
#pragma unroll
        for (int m = 0; m < 4; ++m)
#pragma unroll
            for (int n = 0; n < 4; ++n)
                acc[m][n] = __builtin_amdgcn_mfma_f32_16x16x32_bf16(af[m], bv[n], acc[m][n], 0, 0, 0);

        if (kt + 2 < NT) {
            asm volatile("s_waitcnt vmcnt(4)" ::: "memory");
            __builtin_amdgcn_s_barrier();
            __builtin_amdgcn_sched_barrier(0);
        } else if (kt + 1 < NT) {
            asm volatile("s_waitcnt vmcnt(0)" ::: "memory");
            __builtin_amdgcn_s_barrier();
            __builtin_amdgcn_sched_barrier(0);
        }
    }

    float bload[4];
#pragma unroll
    for (int n = 0; n < 4; ++n) bload[n] = bias[n0 + wn * 64 + n * 16 + l15];

    if (MODE == 0 && z == 2) {
        // V stored transposed: VT[(b*1024 + h*64+d)][s]
#pragma unroll
        for (int m = 0; m < 4; ++m) {
            int row = m0 + wm * 64 + m * 16 + l4 * 4;
#pragma unroll
            for (int n = 0; n < 4; ++n) {
                int col = n0 + wn * 64 + n * 16 + l15;
                float bl = bload[n];
#pragma unroll
                for (int r = 0; r < 4; ++r) {
                    float vv = acc[m][n][r] + bl;
                    int rr = row + r;
                    int bb = rr >> 10, s = rr & 1023;
                    Out[((size_t)(bb * 1024 + col)) * 1024 + s] = (OT)vv;
                }
            }
        }
    } else {
        const float sc = (MODE == 0 && z == 0) ? QSCALE : 1.0f;
#pragma unroll
        for (int m = 0; m < 4; ++m) {
            int row = m0 + wm * 64 + m * 16 + l4 * 4;
#pragma unroll
            for (int n = 0; n < 4; ++n) {
                int col = n0 + wn * 64 + n * 16 + l15;
                float bl = bload[n];
#pragma unroll
                for (int r = 0; r < 4; ++r) {
                    float vv = (acc[m][n][r] + bl) * sc;
                    Out[(size_t)(row + r) * D_MODEL + col] = (OT)vv;
                }
            }
        }
    }
}

// ---------------- Flash attention fwd: intra-block split-KV, 8 waves, chain-merged ----------------
// R9 structure, ONE change: both QK^T chains computed up front (interleaved k0/k1 MFMAs,
// 8 independent dep chains), then per-chain softmax->pack->PV. softmax-A no longer waits
// on a just-issued MFMA chain (pA retired ~8 MFMAs earlier). Peak live +16 regs (pB) vs R9.
__device__ __forceinline__ unsigned pkbf(float lo, float hi2) {
    bf16x2 t; t[0] = (bf16)lo; t[1] = (bf16)hi2;
    return __builtin_bit_cast(unsigned, t);
}

__global__ __launch_bounds__(512, 4)
void attn_fwd(const bf16* __restrict__ Qp, const bf16* __restrict__ Kp,
              const bf16* __restrict__ VT, const int* __restrict__ maskp,
              bf16* __restrict__ ctx) {
    // smem: [0,32K) Kbuf [2buf][2half][4096]; [32K,64K) Vbuf; [64K,68K) madd2; [68K,+64) tflag.
    // Epilogue reuse: [0,32K) Omrg[4][32][64] f32; [32K,+512) Lmrg[4][32] f32.
    __shared__ alignas(16) unsigned char smem[69760];
    bf16* Kbuf = (bf16*)smem;
    bf16* Vbuf = (bf16*)(smem + 32768);
    float* madd2 = (float*)(smem + 65536);
    int* tflag = (int*)(smem + 69632);

    int tid = threadIdx.x;
    int lane = tid & 63, w = tid >> 6;      // 8 waves
    int l31 = lane & 31, hi = lane >> 5;
    int hh = w >> 2, wl = w & 3;            // kv-half, wave-in-half (= q-sub)

    // XCD swizzle: 512 blocks = 8 XCDs x 64; 8 whole heads per XCD.
    int fid = blockIdx.x;
    int xcd = fid & 7, idx = fid >> 3;       // idx 0..63
    int by = xcd * 8 + (idx >> 3);           // head-batch 0..63
    int bx = idx & 7;                        // q-block 0..7
    int b = by >> 4, h = by & 15;
    int q0 = bx * 128;

    // ---- mask precompute: madd2[1024] + per-64-tile flags ----
    {
        madd2[tid] = maskp[b * SEQ + tid] ? 0.f : MASKNEG;
        madd2[512 + tid] = maskp[b * SEQ + 512 + tid] ? 0.f : MASKNEG;
#pragma unroll
        for (int i = 0; i < 2; ++i) {
            int t = w * 2 + i;
            unsigned long long bl = __ballot(maskp[b * SEQ + t * 64 + lane] != 0);
            if (lane == 0) tflag[t] = (bl == ~0ull);
        }
    }

    // Q B-fragments (col=q=lane&31, k-slot ks: d = ks*16 + hi*8 + j); q-sub = wl
    bf16x8 qf[4];
    {
        const bf16* qb = Qp + ((size_t)(b * SEQ + q0 + wl * 32 + l31)) * D_MODEL + h * 64 + hi * 8;
#pragma unroll
        for (int ks = 0; ks < 4; ++ks) qf[ks] = *(const bf16x8*)(qb + ks * 16);
    }

    f32x16 oacc0 = {}, oacc1 = {};
    float lsum = 0.f;

    // stage tile t (0..7) of this wave's half into buf: global tile kt = hh*8 + t
    auto stage = [&](int buf, int t) {
        int kv0 = (hh * 8 + t) * 64;
        bf16* Kd = Kbuf + (size_t)(buf * 2 + hh) * 4096;
        bf16* Vd = Vbuf + (size_t)(buf * 2 + hh) * 4096;
#pragma unroll
        for (int i = 0; i < 2; ++i) {
            int seg = wl * 2 + i;                 // 0..7
            int row = seg * 8 + (lane >> 3);      // 0..63
            int cs = ((lane & 7) ^ (row & 7)) * 8;   // pre-swizzled source chunk
            const bf16* srcK = Kp + ((size_t)(b * SEQ + kv0 + row)) * D_MODEL + h * 64 + cs;
            GLL(srcK, Kd + seg * 512);
            const bf16* srcV = VT + ((size_t)(b * 1024 + h * 64 + row)) * SEQ + kv0 + cs;
            GLL(srcV, Vd + seg * 512);
        }
    };

    // process one 32-kv score chain: exp2+sum, pack, PV (ks = ksb, ksb+1)
    auto half_p = [&](f32x16& p, const float* mbh, int flag, const bf16* Vl, int ksb) -> float {
        float a0 = 0.f, a1 = 0.f, a2 = 0.f, a3 = 0.f;
        if (flag) {
#pragma unroll
            for (int g = 0; g < 4; ++g) {
                float s0 = 0.f;
#pragma unroll
                for (int c = 0; c < 4; ++c) {
                    int r = g * 4 + c;
                    float e = EXP2(p[r]);
                    p[r] = e; s0 += e;
                }
                if (g == 0) a0 = s0; else if (g == 1) a1 = s0;
                else if (g == 2) a2 = s0; else a3 = s0;
            }
        } else {
#pragma unroll
            for (int g = 0; g < 4; ++g) {
                f32x4 mk = *(const f32x4*)(mbh + g * 8 + hi * 4);
                float s0 = 0.f;
#pragma unroll
                for (int c = 0; c < 4; ++c) {
                    int r = g * 4 + c;
                    float e = EXP2(p[r] + mk[c]);
                    p[r] = e; s0 += e;
                }
                if (g == 0) a0 = s0; else if (g == 1) a1 = s0;
                else if (g == 2) a2 = s0; else a3 = s0;
            }
        }
        union FragU { bf16x8 v; unsigned u[4]; };
        FragU A0, A1;
#define PKSW(PV, RA, RB, DST)  { \
            unsigned a_ = pkbf(PV[RA], PV[(RA) + 1]); \
            unsigned b_ = pkbf(PV[RB], PV[(RB) + 1]); \
            auto rr_ = __builtin_amdgcn_permlane32_swap(a_, b_, false, false); \
            DST.u[((RA) & 3) >> 1] = rr_[0]; DST.u[(((RA) & 3) >> 1) + 2] = rr_[1]; }
        PKSW(p, 0, 4,  A0);
        PKSW(p, 2, 6,  A0);
        PKSW(p, 8, 12, A1);
        PKSW(p, 10, 14, A1);
#undef PKSW
        __builtin_amdgcn_s_setprio(1);
#pragma unroll
        for (int i = 0; i < 2; ++i) {
            int ks = ksb + i;
            bf16x8 pav = i ? A1.v : A0.v;
            int sl = ((2 * ks + hi) ^ (l31 & 7)) * 8;
            bf16x8 v0 = *(const bf16x8*)(&Vl[l31 * 64 + sl]);
            bf16x8 v1 = *(const bf16x8*)(&Vl[(32 + l31) * 64 + sl]);
            oacc0 = __builtin_amdgcn_mfma_f32_32x32x16_bf16(pav, v0, oacc0, 0, 0, 0);
            oacc1 = __builtin_amdgcn_mfma_f32_32x32x16_bf16(pav, v1, oacc1, 0, 0, 0);
        }
        __builtin_amdgcn_s_setprio(0);
        return (a0 + a1) + (a2 + a3);
    };

    stage(0, 0);
    __syncthreads();

    for (int t = 0; t < 8; ++t) {
        int cur = t & 1;
        if (t + 1 < 8) stage(cur ^ 1, t + 1);
        int kt = hh * 8 + t;
        const bf16* Kl = Kbuf + (size_t)(cur * 2 + hh) * 4096;
        const bf16* Vl = Vbuf + (size_t)(cur * 2 + hh) * 4096;
        const float* mb = &madd2[kt * 64];
        int flag = tflag[kt];

        // ---- both QK^T chains up front (interleaved: 8 independent dep chains) ----
        f32x16 pA = {}, pB = {};
        __builtin_amdgcn_s_setprio(1);
#pragma unroll
        for (int ks = 0; ks < 4; ++ks) {
            int sl = ((2 * ks + hi) ^ (l31 & 7)) * 8;
            bf16x8 k0 = *(const bf16x8*)(&Kl[l31 * 64 + sl]);
            bf16x8 k1 = *(const bf16x8*)(&Kl[(32 + l31) * 64 + sl]);
            pA = __builtin_amdgcn_mfma_f32_32x32x16_bf16(k0, qf[ks], pA, 0, 0, 0);
            pB = __builtin_amdgcn_mfma_f32_32x32x16_bf16(k1, qf[ks], pB, 0, 0, 0);
        }
        __builtin_amdgcn_s_setprio(0);

        float ts = half_p(pA, mb, flag, Vl, 0);
        ts += half_p(pB, mb + 32, flag, Vl, 2);
        ts += __shfl_xor(ts, 32);
        lsum += ts;

        __syncthreads();
    }

    // ---- merge halves (exp2-space, no max => pure addition), then normalize+store ----
    float* Omrg = (float*)smem;              // [4][32][64]
    float* Lmrg = (float*)(smem + 32768);    // [4][32]
    if (hh == 1) {
#pragma unroll
        for (int g = 0; g < 4; ++g) {
#pragma unroll
            for (int c = 0; c < 4; ++c) {
                int r = g * 4 + c;
                int q = c + g * 8 + hi * 4;      // q-row within sub-tile
                Omrg[wl * 2048 + q * 64 + l31]      = oacc0[r];
                Omrg[wl * 2048 + q * 64 + 32 + l31] = oacc1[r];
            }
        }
        if (hi == 0) Lmrg[wl * 32 + l31] = lsum;
    }
    __syncthreads();
    if (hh == 0) {
        float ltot = lsum + Lmrg[wl * 32 + l31];   // lane l31 holds q=l31's denom
#pragma unroll
        for (int g = 0; g < 4; ++g) {
#pragma unroll
            for (int c = 0; c < 4; ++c) {
                int r = g * 4 + c;
                int q = c + g * 8 + hi * 4;
                float o0 = oacc0[r] + Omrg[wl * 2048 + q * 64 + l31];
                float o1 = oacc1[r] + Omrg[wl * 2048 + q * 64 + 32 + l31];
                float sden = __shfl(ltot, q);
                float inv = 1.0f / sden;
                int qg = q0 + wl * 32 + q;
                size_t base = ((size_t)(b * SEQ + qg)) * D_MODEL + h * 64;
                ctx[base + l31]      = (bf16)(o0 * inv);
                ctx[base + 32 + l31] = (bf16)(o1 * inv);
            }
        }
    }
}

// ---------------- launch ----------------
extern "C" void kernel_launch(void* const* d_in, const int* in_sizes, int n_in,
                              void* d_out, int out_size, void* d_ws, size_t ws_size,
                              hipStream_t stream) {
    const float* q  = (const float*)d_in[0];
    const float* k  = (const float*)d_in[1];
    const float* v  = (const float*)d_in[2];
    const int* mask = (const int*)d_in[3];
    const float* Wq = (const float*)d_in[4];
    const float* bq = (const float*)d_in[5];
    const float* Wk = (const float*)d_in[6];
    const float* bk = (const float*)d_in[7];
    const float* Wv = (const float*)d_in[8];
    const float* bv = (const float*)d_in[9];
    const float* Wo = (const float*)d_in[10];
    const float* bo = (const float*)d_in[11];
    float* out = (float*)d_out;

    char* ws = (char*)d_ws;
    size_t szQKV = (size_t)MTOT * D_MODEL * sizeof(bf16);   // 8 MB
    size_t szW = (size_t)D_MODEL * D_MODEL * sizeof(bf16);  // 2 MB
    bf16* qb  = (bf16*)ws; ws += szQKV;
    bf16* kb  = (bf16*)ws; ws += szQKV;
    bf16* vb  = (bf16*)ws; ws += szQKV;
    bf16* Wqb = (bf16*)ws; ws += szW;
    bf16* Wkb = (bf16*)ws; ws += szW;
    bf16* Wvb = (bf16*)ws; ws += szW;
    bf16* Wob = (bf16*)ws; ws += szW;
    bf16* Qp  = (bf16*)ws; ws += szQKV;
    bf16* Kp  = (bf16*)ws; ws += szQKV;
    bf16* VT  = (bf16*)ws; ws += szQKV;   // transposed V: [B][H][64][SEQ]
    bf16* ctx = (bf16*)ws; ws += szQKV;

    dim3 gc(512, 7, 1);
    cast_all<<<gc, 256, 0, stream>>>(q, k, v, Wq, Wk, Wv, Wo,
                                     qb, kb, vb, Wqb, Wkb, Wvb, Wob);

    dim3 g1(MTOT / 128, D_MODEL / 128, 3);
    gemm_bt<bf16, 0><<<g1, 256, 0, stream>>>(qb, kb, vb, Wqb, Wkb, Wvb,
                                             bq, bk, bv, Qp, Kp, VT);

    attn_fwd<<<dim3(512), 512, 0, stream>>>(Qp, Kp, VT, mask, ctx);

    dim3 g3(MTOT / 128, D_MODEL / 128, 1);
    gemm_bt<float, 1><<<g3, 256, 0, stream>>>(ctx, ctx, ctx, Wob, Wob, Wob,
                                              bo, bo, bo, out, out, out);
}

// Round 15
// 103.397 us; speedup vs baseline: 1.6032x; 1.0080x over previous
//
#include <hip/hip_runtime.h>
#include <hip/hip_bf16.h>
#include <math.h>

typedef __bf16 bf16;
typedef __bf16 bf16x8 __attribute__((ext_vector_type(8)));
typedef __bf16 bf16x2 __attribute__((ext_vector_type(2)));
typedef float f32x4 __attribute__((ext_vector_type(4)));
typedef float f32x16 __attribute__((ext_vector_type(16)));

#define D_MODEL 1024
#define SEQ 1024
#define BATCH 4
#define NHEAD 16
#define MTOT (BATCH*SEQ)   // 4096

// scores computed in exp2-space: fold 1/sqrt(64) * log2(e) into Q projection
#define QSCALE 0.18033688011112042f
#define MASKNEG -1e9f
#define EXP2(x) __builtin_amdgcn_exp2f(x)

#define GLL(SRC, DST) __builtin_amdgcn_global_load_lds( \
    (const __attribute__((address_space(1))) void*)(SRC), \
    (__attribute__((address_space(3))) void*)(DST), 16, 0, 0)

// ---------------- fused f32 -> bf16 casts (7 tensors, one launch; at HBM ceiling) ----------------
__global__ void cast_all(const float* __restrict__ s0, const float* __restrict__ s1,
                         const float* __restrict__ s2, const float* __restrict__ s3,
                         const float* __restrict__ s4, const float* __restrict__ s5,
                         const float* __restrict__ s6,
                         bf16* d0, bf16* d1, bf16* d2, bf16* d3, bf16* d4, bf16* d5, bf16* d6) {
    int z = blockIdx.y;
    const float* s; bf16* d; int n;
    switch (z) {
        case 0: s = s0; d = d0; n = MTOT * D_MODEL; break;
        case 1: s = s1; d = d1; n = MTOT * D_MODEL; break;
        case 2: s = s2; d = d2; n = MTOT * D_MODEL; break;
        case 3: s = s3; d = d3; n = D_MODEL * D_MODEL; break;
        case 4: s = s4; d = d4; n = D_MODEL * D_MODEL; break;
        case 5: s = s5; d = d5; n = D_MODEL * D_MODEL; break;
        default: s = s6; d = d6; n = D_MODEL * D_MODEL; break;
    }
    int idx = (blockIdx.x * blockDim.x + threadIdx.x) * 8;
    int stride = gridDim.x * blockDim.x * 8;
    for (int i = idx; i < n; i += stride) {
        const float4* p = (const float4*)(s + i);
        float4 a = p[0], b = p[1];
        bf16x8 o;
        o[0] = (bf16)a.x; o[1] = (bf16)a.y; o[2] = (bf16)a.z; o[3] = (bf16)a.w;
        o[4] = (bf16)b.x; o[5] = (bf16)b.y; o[6] = (bf16)b.z; o[7] = (bf16)b.w;
        *(bf16x8*)(d + i) = o;
    }
}

// ---------------- GEMM: C[M,N] = A[M,K] @ W[N,K]^T + bias (R11 champion) ----------------
// 3-buffer LDS, prefetch distance 2, counted vmcnt: stage(kt+2) -> compute(kt) ->
// s_waitcnt vmcnt(4) -> raw s_barrier. Buffer rotation mod 3 => race-free.
template<typename OT, int MODE>
__global__ __launch_bounds__(256, 3)
void gemm_bt(const bf16* __restrict__ A0, const bf16* __restrict__ A1, const bf16* __restrict__ A2,
             const bf16* __restrict__ W0, const bf16* __restrict__ W1, const bf16* __restrict__ W2,
             const float* __restrict__ bias0, const float* __restrict__ bias1, const float* __restrict__ bias2,
             OT* __restrict__ O0, OT* __restrict__ O1, OT* __restrict__ O2) {
    constexpr int BK = 32;
    constexpr int K = D_MODEL;
    constexpr int NT = K / BK;   // 32
    __shared__ alignas(16) bf16 As[3][128 * BK];
    __shared__ alignas(16) bf16 Bs[3][128 * BK];

    int z = (MODE == 0) ? blockIdx.z : 0;
    const bf16* A = (z == 0) ? A0 : (z == 1) ? A1 : A2;
    const bf16* W = (z == 0) ? W0 : (z == 1) ? W1 : W2;
    const float* bias = (z == 0) ? bias0 : (z == 1) ? bias1 : bias2;
    OT* Out = (z == 0) ? O0 : (z == 1) ? O1 : O2;

    int tid = threadIdx.x;
    int lane = tid & 63, w = tid >> 6;
    int l15 = lane & 15, l4 = lane >> 4;
    int m0 = blockIdx.x * 128;
    int n0 = blockIdx.y * 128;
    int wm = w >> 1, wn = w & 1;

    f32x4 acc[4][4] = {};

    int srow = lane >> 2;
    int scol = (lane & 3) * 8;

    auto stage = [&](int buf, int kt) {
#pragma unroll
        for (int i = 0; i < 2; ++i) {
            int seg = w * 2 + i;
            int row = seg * 16 + srow;
            const bf16* srcA = A + (size_t)(m0 + row) * K + kt * BK + scol;
            const bf16* srcB = W + (size_t)(n0 + row) * K + kt * BK + scol;
            GLL(srcA, &As[buf][seg * 512]);
            GLL(srcB, &Bs[buf][seg * 512]);
        }
    };

    stage(0, 0);
    stage(1, 1);
    asm volatile("s_waitcnt vmcnt(4)" ::: "memory");
    __builtin_amdgcn_s_barrier();
    __builtin_amdgcn_sched_barrier(0);

    for (int kt = 0; kt < NT; ++kt) {
        int cur = kt - (kt / 3) * 3;           // kt % 3
        if (kt + 2 < NT) stage(kt + 2 - ((kt + 2) / 3) * 3, kt + 2);

        const bf16* pa = &As[cur][(wm * 64 + l15) * BK + l4 * 8];
        const bf16* pb = &Bs[cur][(wn * 64 + l15) * BK + l4 * 8];
        bf16x8 af[4], bv[4];
#pragma unroll
        for (int m = 0; m < 4; ++m) af[m] = *(const bf16x8*)(pa + m * 16 * BK);
#pragma unroll
        for (int n = 0; n < 4; ++n) bv[n] = *(const bf16x8*)(pb + n * 16 * BK);
#pragma unroll
        for (int m = 0; m < 4; ++m)
#pragma unroll
            for (int n = 0; n < 4; ++n)
                acc[m][n] = __builtin_amdgcn_mfma_f32_16x16x32_bf16(af[m], bv[n], acc[m][n], 0, 0, 0);

        if (kt + 2 < NT) {
            asm volatile("s_waitcnt vmcnt(4)" ::: "memory");
            __builtin_amdgcn_s_barrier();
            __builtin_amdgcn_sched_barrier(0);
        } else if (kt + 1 < NT) {
            asm volatile("s_waitcnt vmcnt(0)" ::: "memory");
            __builtin_amdgcn_s_barrier();
            __builtin_amdgcn_sched_barrier(0);
        }
    }

    float bload[4];
#pragma unroll
    for (int n = 0; n < 4; ++n) bload[n] = bias[n0 + wn * 64 + n * 16 + l15];

    if (MODE == 0 && z == 2) {
        // V stored transposed: VT[(b*1024 + h*64+d)][s]
#pragma unroll
        for (int m = 0; m < 4; ++m) {
            int row = m0 + wm * 64 + m * 16 + l4 * 4;
#pragma unroll
            for (int n = 0; n < 4; ++n) {
                int col = n0 + wn * 64 + n * 16 + l15;
                float bl = bload[n];
#pragma unroll
                for (int r = 0; r < 4; ++r) {
                    float vv = acc[m][n][r] + bl;
                    int rr = row + r;
                    int bb = rr >> 10, s = rr & 1023;
                    Out[((size_t)(bb * 1024 + col)) * 1024 + s] = (OT)vv;
                }
            }
        }
    } else {
        const float sc = (MODE == 0 && z == 0) ? QSCALE : 1.0f;
#pragma unroll
        for (int m = 0; m < 4; ++m) {
            int row = m0 + wm * 64 + m * 16 + l4 * 4;
#pragma unroll
            for (int n = 0; n < 4; ++n) {
                int col = n0 + wn * 64 + n * 16 + l15;
                float bl = bload[n];
#pragma unroll
                for (int r = 0; r < 4; ++r) {
                    float vv = (acc[m][n][r] + bl) * sc;
                    Out[(size_t)(row + r) * D_MODEL + col] = (OT)vv;
                }
            }
        }
    }
}

// ---------------- Flash attention fwd: intra-block split-KV, 8 waves, LOW-VGPR (R9 champion) ----------------
// Waves 0-3: kv [0,512); waves 4-7: kv [512,1024); same 128 q-rows. Exp2-space no-max
// softmax => halves merge by PURE ADDITION in LDS epilogue. 16 waves/CU.
// Each 64-kv tile processed as TWO 32-kv chains (QK^T -> exp2 -> pack -> PV), so only
// ONE f32x16 score block is live at a time -> no spill at (512,4) launch bounds.
__device__ __forceinline__ unsigned pkbf(float lo, float hi2) {
    bf16x2 t; t[0] = (bf16)lo; t[1] = (bf16)hi2;
    return __builtin_bit_cast(unsigned, t);
}

__global__ __launch_bounds__(512, 4)
void attn_fwd(const bf16* __restrict__ Qp, const bf16* __restrict__ Kp,
              const bf16* __restrict__ VT, const int* __restrict__ maskp,
              bf16* __restrict__ ctx) {
    // smem: [0,32K) Kbuf [2buf][2half][4096]; [32K,64K) Vbuf; [64K,68K) madd2; [68K,+64) tflag.
    // Epilogue reuse: [0,32K) Omrg[4][32][64] f32; [32K,+512) Lmrg[4][32] f32.
    __shared__ alignas(16) unsigned char smem[69760];
    bf16* Kbuf = (bf16*)smem;
    bf16* Vbuf = (bf16*)(smem + 32768);
    float* madd2 = (float*)(smem + 65536);
    int* tflag = (int*)(smem + 69632);

    int tid = threadIdx.x;
    int lane = tid & 63, w = tid >> 6;      // 8 waves
    int l31 = lane & 31, hi = lane >> 5;
    int hh = w >> 2, wl = w & 3;            // kv-half, wave-in-half (= q-sub)

    // XCD swizzle: 512 blocks = 8 XCDs x 64; 8 whole heads per XCD.
    int fid = blockIdx.x;
    int xcd = fid & 7, idx = fid >> 3;       // idx 0..63
    int by = xcd * 8 + (idx >> 3);           // head-batch 0..63
    int bx = idx & 7;                        // q-block 0..7
    int b = by >> 4, h = by & 15;
    int q0 = bx * 128;

    // ---- mask precompute: madd2[1024] + per-64-tile flags ----
    {
        madd2[tid] = maskp[b * SEQ + tid] ? 0.f : MASKNEG;
        madd2[512 + tid] = maskp[b * SEQ + 512 + tid] ? 0.f : MASKNEG;
#pragma unroll
        for (int i = 0; i < 2; ++i) {
            int t = w * 2 + i;
            unsigned long long bl = __ballot(maskp[b * SEQ + t * 64 + lane] != 0);
            if (lane == 0) tflag[t] = (bl == ~0ull);
        }
    }

    // Q B-fragments (col=q=lane&31, k-slot ks: d = ks*16 + hi*8 + j); q-sub = wl
    bf16x8 qf[4];
    {
        const bf16* qb = Qp + ((size_t)(b * SEQ + q0 + wl * 32 + l31)) * D_MODEL + h * 64 + hi * 8;
#pragma unroll
        for (int ks = 0; ks < 4; ++ks) qf[ks] = *(const bf16x8*)(qb + ks * 16);
    }

    f32x16 oacc0 = {}, oacc1 = {};
    float lsum = 0.f;

    // stage tile t (0..7) of this wave's half into buf: global tile kt = hh*8 + t
    auto stage = [&](int buf, int t) {
        int kv0 = (hh * 8 + t) * 64;
        bf16* Kd = Kbuf + (size_t)(buf * 2 + hh) * 4096;
        bf16* Vd = Vbuf + (size_t)(buf * 2 + hh) * 4096;
#pragma unroll
        for (int i = 0; i < 2; ++i) {
            int seg = wl * 2 + i;                 // 0..7
            int row = seg * 8 + (lane >> 3);      // 0..63
            int cs = ((lane & 7) ^ (row & 7)) * 8;   // pre-swizzled source chunk
            const bf16* srcK = Kp + ((size_t)(b * SEQ + kv0 + row)) * D_MODEL + h * 64 + cs;
            GLL(srcK, Kd + seg * 512);
            const bf16* srcV = VT + ((size_t)(b * 1024 + h * 64 + row)) * SEQ + kv0 + cs;
            GLL(srcV, Vd + seg * 512);
        }
    };

    // process one 32-kv score chain: exp2+sum, pack, PV (ks = ksb, ksb+1)
    auto half_p = [&](f32x16& p, const float* mbh, int flag, const bf16* Vl, int ksb) -> float {
        float a0 = 0.f, a1 = 0.f, a2 = 0.f, a3 = 0.f;
        if (flag) {
#pragma unroll
            for (int g = 0; g < 4; ++g) {
                float s0 = 0.f;
#pragma unroll
                for (int c = 0; c < 4; ++c) {
                    int r = g * 4 + c;
                    float e = EXP2(p[r]);
                    p[r] = e; s0 += e;
                }
                if (g == 0) a0 = s0; else if (g == 1) a1 = s0;
                else if (g == 2) a2 = s0; else a3 = s0;
            }
        } else {
#pragma unroll
            for (int g = 0; g < 4; ++g) {
                f32x4 mk = *(const f32x4*)(mbh + g * 8 + hi * 4);
                float s0 = 0.f;
#pragma unroll
                for (int c = 0; c < 4; ++c) {
                    int r = g * 4 + c;
                    float e = EXP2(p[r] + mk[c]);
                    p[r] = e; s0 += e;
                }
                if (g == 0) a0 = s0; else if (g == 1) a1 = s0;
                else if (g == 2) a2 = s0; else a3 = s0;
            }
        }
        union FragU { bf16x8 v; unsigned u[4]; };
        FragU A0, A1;
#define PKSW(PV, RA, RB, DST)  { \
            unsigned a_ = pkbf(PV[RA], PV[(RA) + 1]); \
            unsigned b_ = pkbf(PV[RB], PV[(RB) + 1]); \
            auto rr_ = __builtin_amdgcn_permlane32_swap(a_, b_, false, false); \
            DST.u[((RA) & 3) >> 1] = rr_[0]; DST.u[(((RA) & 3) >> 1) + 2] = rr_[1]; }
        PKSW(p, 0, 4,  A0);
        PKSW(p, 2, 6,  A0);
        PKSW(p, 8, 12, A1);
        PKSW(p, 10, 14, A1);
#undef PKSW
        __builtin_amdgcn_s_setprio(1);
#pragma unroll
        for (int i = 0; i < 2; ++i) {
            int ks = ksb + i;
            bf16x8 pav = i ? A1.v : A0.v;
            int sl = ((2 * ks + hi) ^ (l31 & 7)) * 8;
            bf16x8 v0 = *(const bf16x8*)(&Vl[l31 * 64 + sl]);
            bf16x8 v1 = *(const bf16x8*)(&Vl[(32 + l31) * 64 + sl]);
            oacc0 = __builtin_amdgcn_mfma_f32_32x32x16_bf16(pav, v0, oacc0, 0, 0, 0);
            oacc1 = __builtin_amdgcn_mfma_f32_32x32x16_bf16(pav, v1, oacc1, 0, 0, 0);
        }
        __builtin_amdgcn_s_setprio(0);
        return (a0 + a1) + (a2 + a3);
    };

    stage(0, 0);
    __syncthreads();

    for (int t = 0; t < 8; ++t) {
        int cur = t & 1;
        if (t + 1 < 8) stage(cur ^ 1, t + 1);
        int kt = hh * 8 + t;
        const bf16* Kl = Kbuf + (size_t)(cur * 2 + hh) * 4096;
        const bf16* Vl = Vbuf + (size_t)(cur * 2 + hh) * 4096;
        const float* mb = &madd2[kt * 64];
        int flag = tflag[kt];

        float ts;
        {   // chain A: kv rows [0,32) of tile
            f32x16 p = {};
            __builtin_amdgcn_s_setprio(1);
#pragma unroll
            for (int ks = 0; ks < 4; ++ks) {
                int sl = ((2 * ks + hi) ^ (l31 & 7)) * 8;
                bf16x8 k0 = *(const bf16x8*)(&Kl[l31 * 64 + sl]);
                p = __builtin_amdgcn_mfma_f32_32x32x16_bf16(k0, qf[ks], p, 0, 0, 0);
            }
            __builtin_amdgcn_s_setprio(0);
            ts = half_p(p, mb, flag, Vl, 0);
        }
        {   // chain B: kv rows [32,64) of tile
            f32x16 p = {};
            __builtin_amdgcn_s_setprio(1);
#pragma unroll
            for (int ks = 0; ks < 4; ++ks) {
                int sl = ((2 * ks + hi) ^ (l31 & 7)) * 8;
                bf16x8 k1 = *(const bf16x8*)(&Kl[(32 + l31) * 64 + sl]);
                p = __builtin_amdgcn_mfma_f32_32x32x16_bf16(k1, qf[ks], p, 0, 0, 0);
            }
            __builtin_amdgcn_s_setprio(0);
            ts += half_p(p, mb + 32, flag, Vl, 2);
        }
        ts += __shfl_xor(ts, 32);
        lsum += ts;

        __syncthreads();
    }

    // ---- merge halves (exp2-space, no max => pure addition), then normalize+store ----
    float* Omrg = (float*)smem;              // [4][32][64]
    float* Lmrg = (float*)(smem + 32768);    // [4][32]
    if (hh == 1) {
#pragma unroll
        for (int g = 0; g < 4; ++g) {
#pragma unroll
            for (int c = 0; c < 4; ++c) {
                int r = g * 4 + c;
                int q = c + g * 8 + hi * 4;      // q-row within sub-tile
                Omrg[wl * 2048 + q * 64 + l31]      = oacc0[r];
                Omrg[wl * 2048 + q * 64 + 32 + l31] = oacc1[r];
            }
        }
        if (hi == 0) Lmrg[wl * 32 + l31] = lsum;
    }
    __syncthreads();
    if (hh == 0) {
        float ltot = lsum + Lmrg[wl * 32 + l31];   // lane l31 holds q=l31's denom
#pragma unroll
        for (int g = 0; g < 4; ++g) {
#pragma unroll
            for (int c = 0; c < 4; ++c) {
                int r = g * 4 + c;
                int q = c + g * 8 + hi * 4;
                float o0 = oacc0[r] + Omrg[wl * 2048 + q * 64 + l31];
                float o1 = oacc1[r] + Omrg[wl * 2048 + q * 64 + 32 + l31];
                float sden = __shfl(ltot, q);
                float inv = 1.0f / sden;
                int qg = q0 + wl * 32 + q;
                size_t base = ((size_t)(b * SEQ + qg)) * D_MODEL + h * 64;
                ctx[base + l31]      = (bf16)(o0 * inv);
                ctx[base + 32 + l31] = (bf16)(o1 * inv);
            }
        }
    }
}

// ---------------- launch ----------------
extern "C" void kernel_launch(void* const* d_in, const int* in_sizes, int n_in,
                              void* d_out, int out_size, void* d_ws, size_t ws_size,
                              hipStream_t stream) {
    const float* q  = (const float*)d_in[0];
    const float* k  = (const float*)d_in[1];
    const float* v  = (const float*)d_in[2];
    const int* mask = (const int*)d_in[3];
    const float* Wq = (const float*)d_in[4];
    const float* bq = (const float*)d_in[5];
    const float* Wk = (const float*)d_in[6];
    const float* bk = (const float*)d_in[7];
    const float* Wv = (const float*)d_in[8];
    const float* bv = (const float*)d_in[9];
    const float* Wo = (const float*)d_in[10];
    const float* bo = (const float*)d_in[11];
    float* out = (float*)d_out;

    char* ws = (char*)d_ws;
    size_t szQKV = (size_t)MTOT * D_MODEL * sizeof(bf16);   // 8 MB
    size_t szW = (size_t)D_MODEL * D_MODEL * sizeof(bf16);  // 2 MB
    bf16* qb  = (bf16*)ws; ws += szQKV;
    bf16* kb  = (bf16*)ws; ws += szQKV;
    bf16* vb  = (bf16*)ws; ws += szQKV;
    bf16* Wqb = (bf16*)ws; ws += szW;
    bf16* Wkb = (bf16*)ws; ws += szW;
    bf16* Wvb = (bf16*)ws; ws += szW;
    bf16* Wob = (bf16*)ws; ws += szW;
    bf16* Qp  = (bf16*)ws; ws += szQKV;
    bf16* Kp  = (bf16*)ws; ws += szQKV;
    bf16* VT  = (bf16*)ws; ws += szQKV;   // transposed V: [B][H][64][SEQ]
    bf16* ctx = (bf16*)ws; ws += szQKV;

    dim3 gc(512, 7, 1);
    cast_all<<<gc, 256, 0, stream>>>(q, k, v, Wq, Wk, Wv, Wo,
                                     qb, kb, vb, Wqb, Wkb, Wvb, Wob);

    dim3 g1(MTOT / 128, D_MODEL / 128, 3);
    gemm_bt<bf16, 0><<<g1, 256, 0, stream>>>(qb, kb, vb, Wqb, Wkb, Wvb,
                                             bq, bk, bv, Qp, Kp, VT);

    attn_fwd<<<dim3(512), 512, 0, stream>>>(Qp, Kp, VT, mask, ctx);

    dim3 g3(MTOT / 128, D_MODEL / 128, 1);
    gemm_bt<float, 1><<<g3, 256, 0, stream>>>(ctx, ctx, ctx, Wob, Wob, Wob,
                                              bo, bo, bo, out, out, out);
}